// Round 1
// baseline (676.049 us; speedup 1.0000x reference)
//
#include <hip/hip_runtime.h>
#include <hip/hip_bf16.h>

#define ROWS 8192
#define COLS 16384
#define BLOCK 256

// Kernel 1: one block per row. Row = 16384 floats = 4096 float4.
// 256 threads -> 16 float4 per thread, fully coalesced.
__global__ __launch_bounds__(BLOCK) void row_hinge_kernel(const float* __restrict__ B,
                                                          float* __restrict__ ws) {
    const int row = blockIdx.x;
    const float4* rowp = (const float4*)(B + (size_t)row * COLS);
    const int tid = threadIdx.x;

    float s = 0.0f;
#pragma unroll
    for (int it = 0; it < (COLS / 4) / BLOCK; ++it) {
        float4 v = rowp[tid + it * BLOCK];
        s += (v.x + v.y) + (v.z + v.w);
    }

    // wave-64 reduction
#pragma unroll
    for (int off = 32; off > 0; off >>= 1)
        s += __shfl_down(s, off, 64);

    __shared__ float wsum[BLOCK / 64];
    const int wave = tid >> 6;
    const int lane = tid & 63;
    if (lane == 0) wsum[wave] = s;
    __syncthreads();

    if (tid == 0) {
        float rs = 0.0f;
#pragma unroll
        for (int w = 0; w < BLOCK / 64; ++w) rs += wsum[w];
        float h = rs - 1.0f;
        ws[row] = h > 0.0f ? h : 0.0f;
    }
}

// Kernel 2: reduce 8192 hinges -> mean -> d_out[0]. Single block.
__global__ __launch_bounds__(BLOCK) void final_reduce_kernel(const float* __restrict__ ws,
                                                             float* __restrict__ out) {
    const int tid = threadIdx.x;
    float s = 0.0f;
#pragma unroll
    for (int i = tid; i < ROWS; i += BLOCK)
        s += ws[i];

#pragma unroll
    for (int off = 32; off > 0; off >>= 1)
        s += __shfl_down(s, off, 64);

    __shared__ float wsum[BLOCK / 64];
    const int wave = tid >> 6;
    const int lane = tid & 63;
    if (lane == 0) wsum[wave] = s;
    __syncthreads();

    if (tid == 0) {
        float total = 0.0f;
#pragma unroll
        for (int w = 0; w < BLOCK / 64; ++w) total += wsum[w];
        out[0] = total * (1.0f / (float)ROWS);  // PENALTY_B = 1.0
    }
}

extern "C" void kernel_launch(void* const* d_in, const int* in_sizes, int n_in,
                              void* d_out, int out_size, void* d_ws, size_t ws_size,
                              hipStream_t stream) {
    const float* B = (const float*)d_in[0];
    float* out = (float*)d_out;
    float* ws = (float*)d_ws;  // needs ROWS*4 = 32 KiB

    row_hinge_kernel<<<ROWS, BLOCK, 0, stream>>>(B, ws);
    final_reduce_kernel<<<1, BLOCK, 0, stream>>>(ws, out);
}